// Round 10
// baseline (42.525 us; speedup 1.0000x reference)
//
#include <hip/hip_runtime.h>

// MLPKANLayer: per-(in,out) scalar MLP 1->2->2->1 (relu), summed over in.
// x:[8192,64] f32 -> out:[8192,64] f32.
//
// R9 = SLOPE DIAGNOSTIC on the R8 structure. Three different kernel bodies
// (R1/R7/R8) all measured 17-18 us while body models say 5.5-7 us; the
// rocprof top-k cut hides the kernel row behind 40-us harness memsets, so
// dur cannot be decomposed into overhead vs body from the bench alone.
// This round runs the row+reduce pass REPS=4 times in-kernel:
//     dur = overhead + preload + REPS * body
// so body = (dur_R9 - dur_R8) / 3. pin() on the x values makes each pass's
// VALU chain opaque to CSE/hoisting (the compiler cannot compute once and
// re-store). Every pass writes the same correct output -> deterministic,
// replay-safe. Intentionally slower this round; next round reverts to the
// winner of {Model A: near-roofline cleanup, Model B: body attack}.

#define IN_SIZE  64
#define OUT_SIZE 64
#define BATCH    8192

constexpr int WAVES   = 16;   // waves per block
constexpr int I_CHUNK = 4;    // i's per wave (WAVES * I_CHUNK = 64)
constexpr int BT      = 32;   // batch rows per block (grid = 256 = 1 block/CU)
constexpr int REPS    = 4;    // diagnostic repeat count

__device__ __forceinline__ void pin(float& v) {
    asm volatile("" : "+v"(v));   // value becomes opaque: blocks CSE/hoist/sink
}

__device__ __forceinline__ void conn(float xv, float2 W1, float2 B1,
                                     float4 W2, float2 B2, float2 W3,
                                     float& s) {
    const float h0 = fmaxf(fmaf(xv, W1.x, B1.x), 0.f);
    const float h1 = fmaxf(fmaf(xv, W1.y, B1.y), 0.f);
    float u0 = fmaf(h1, W2.y, fmaf(h0, W2.x, B2.x));
    float u1 = fmaf(h1, W2.w, fmaf(h0, W2.z, B2.y));
    u0 = fmaxf(u0, 0.f);
    u1 = fmaxf(u1, 0.f);
    s = fmaf(u0, W3.x, s);
    s = fmaf(u1, W3.y, s);
}

__global__ __launch_bounds__(1024) void kan_kernel(
    const float* __restrict__ x,
    const float* __restrict__ w1, const float* __restrict__ b1,
    const float* __restrict__ w2, const float* __restrict__ b2,
    const float* __restrict__ w3, const float* __restrict__ b3,
    float* __restrict__ out)
{
    const int tid   = threadIdx.x;
    const int o     = tid & 63;
    const int wv    = __builtin_amdgcn_readfirstlane(tid >> 6); // provably uniform
    const int brow0 = blockIdx.x * BT;

    __shared__ float ps[WAVES][BT][OUT_SIZE];   // 128 KiB, unpadded

    // Preload this wave's i-chunk weights into registers (coalesced per lane=o).
    const int i0 = wv * I_CHUNK;
    float2 W1[I_CHUNK], B1[I_CHUNK], B2[I_CHUNK], W3[I_CHUNK];
    float4 W2[I_CHUNK];
    float bacc = 0.f;
    #pragma unroll
    for (int ic = 0; ic < I_CHUNK; ++ic) {
        const int base = (i0 + ic) * OUT_SIZE + o;
        W1[ic] = reinterpret_cast<const float2*>(w1)[base];
        B1[ic] = reinterpret_cast<const float2*>(b1)[base];
        W2[ic] = reinterpret_cast<const float4*>(w2)[base];
        B2[ic] = reinterpret_cast<const float2*>(b2)[base];
        W3[ic] = reinterpret_cast<const float2*>(w3)[base];
        bacc  += b3[base];
    }

    const float* xrow = x + brow0 * IN_SIZE + i0;

    for (int k = 0; k < REPS; ++k) {
        // Rows: wave-uniform 16-B x loads; pin() makes xa opaque per pass so
        // the whole conn chain re-executes (no cross-pass CSE).
        #pragma unroll 8
        for (int r = 0; r < BT; ++r) {
            float4 xa = *reinterpret_cast<const float4*>(xrow + r * IN_SIZE);
            pin(xa.x); pin(xa.y); pin(xa.z); pin(xa.w);
            float s = bacc;
            conn(xa.x, W1[0], B1[0], W2[0], B2[0], W3[0], s);
            conn(xa.y, W1[1], B1[1], W2[1], B2[1], W3[1], s);
            conn(xa.z, W1[2], B1[2], W2[2], B2[2], W3[2], s);
            conn(xa.w, W1[3], B1[3], W2[3], B2[3], W3[3], s);
            ps[wv][r][o] = s;
        }

        __syncthreads();   // ps ready

        // Reduce 16 wave-partials per (r,o): 2048 outputs, 1024 threads.
        #pragma unroll
        for (int t = tid; t < BT * OUT_SIZE; t += 1024) {
            const int r = t >> 6, oo = t & 63;
            float v = 0.f;
            #pragma unroll
            for (int w = 0; w < WAVES; ++w) v += ps[w][r][oo];
            out[brow0 * OUT_SIZE + t] = v;
        }

        __syncthreads();   // ps reusable for next pass
    }
}

extern "C" void kernel_launch(void* const* d_in, const int* in_sizes, int n_in,
                              void* d_out, int out_size, void* d_ws, size_t ws_size,
                              hipStream_t stream) {
    const float* x  = (const float*)d_in[0];
    const float* w1 = (const float*)d_in[1];
    const float* b1 = (const float*)d_in[2];
    const float* w2 = (const float*)d_in[3];
    const float* b2 = (const float*)d_in[4];
    const float* w3 = (const float*)d_in[5];
    const float* b3 = (const float*)d_in[6];
    float* out = (float*)d_out;

    const int grid = BATCH / BT;   // 256 blocks x 1024 threads = 1 block/CU
    kan_kernel<<<grid, 1024, 0, stream>>>(x, w1, b1, w2, b2, w3, b3, out);
}

// Round 11
// 16.623 us; speedup vs baseline: 2.5582x; 2.5582x over previous
//
#include <hip/hip_runtime.h>

// MLPKANLayer: per-(in,out) scalar MLP 1->2->2->1 (relu), summed over in.
// x:[8192,64] f32 -> out:[8192,64] f32.
//
// R10: occupancy attack, informed by R9's slope diagnostic:
//   dur = intercept (~9.6 us: launch + preload + tail) + body (~8.2 us)
//   R9 profile: VGPR=52 (weights resident, sinking theory dead, pins gone),
//   VALUBusy 84%, Occupancy 37% (ps=128 KiB -> 1 block/CU -> 16/32 waves).
// Change: BT 32->16 -> ps[16][16][64] = 64 KiB -> 2 blocks/CU resident
// (grid 512). Wave occupancy 16->32 waves/CU (= 8/SIMD, the max; VGPR 52
// fits the 64-reg cap enforced by __launch_bounds__(1024, 8)). Effects:
// (a) VALU issue efficiency 84% -> ~95% (more waves to cover SMEM/LDS
// latency), (b) one block's weight preload overlaps the other's compute,
// shrinking the intercept, (c) smaller tail.
// 12 VALU ops/conn is algebraically minimal (8 FMA + 4 max; no packed-f32
// FLOP gain on CDNA4 -- 157.3 TF spec = scalar v_fma rate; PWL refactor has
// unbounded breakpoints). Memory side is done: FETCH ~3 MB ideal, 0 bank
// conflicts. If this lands >=16.5 us the floor is launch overhead ->
// declare practical roofline.

#define IN_SIZE  64
#define OUT_SIZE 64
#define BATCH    8192

constexpr int WAVES   = 16;   // waves per block
constexpr int I_CHUNK = 4;    // i's per wave (WAVES * I_CHUNK = 64)
constexpr int BT      = 16;   // batch rows per block (grid = 512 = 2 blocks/CU)

__device__ __forceinline__ void conn(float xv, float2 W1, float2 B1,
                                     float4 W2, float2 B2, float2 W3,
                                     float& s) {
    const float h0 = fmaxf(fmaf(xv, W1.x, B1.x), 0.f);
    const float h1 = fmaxf(fmaf(xv, W1.y, B1.y), 0.f);
    float u0 = fmaf(h1, W2.y, fmaf(h0, W2.x, B2.x));
    float u1 = fmaf(h1, W2.w, fmaf(h0, W2.z, B2.y));
    u0 = fmaxf(u0, 0.f);
    u1 = fmaxf(u1, 0.f);
    s = fmaf(u0, W3.x, s);
    s = fmaf(u1, W3.y, s);
}

__global__ __launch_bounds__(1024, 8) void kan_kernel(
    const float* __restrict__ x,
    const float* __restrict__ w1, const float* __restrict__ b1,
    const float* __restrict__ w2, const float* __restrict__ b2,
    const float* __restrict__ w3, const float* __restrict__ b3,
    float* __restrict__ out)
{
    const int tid   = threadIdx.x;
    const int o     = tid & 63;
    const int wv    = __builtin_amdgcn_readfirstlane(tid >> 6); // provably uniform
    const int brow0 = blockIdx.x * BT;

    __shared__ float ps[WAVES][BT][OUT_SIZE];   // 16*16*64*4 = 64 KiB

    // Preload this wave's i-chunk weights into registers (coalesced per lane=o).
    const int i0 = wv * I_CHUNK;
    float2 W1[I_CHUNK], B1[I_CHUNK], B2[I_CHUNK], W3[I_CHUNK];
    float4 W2[I_CHUNK];
    float bacc = 0.f;   // this wave's share of sum_i b3[i][o]
    #pragma unroll
    for (int ic = 0; ic < I_CHUNK; ++ic) {
        const int base = (i0 + ic) * OUT_SIZE + o;
        W1[ic] = reinterpret_cast<const float2*>(w1)[base];
        B1[ic] = reinterpret_cast<const float2*>(b1)[base];
        W2[ic] = reinterpret_cast<const float4*>(w2)[base];
        B2[ic] = reinterpret_cast<const float2*>(b2)[base];
        W3[ic] = reinterpret_cast<const float2*>(w3)[base];
        bacc  += b3[base];
    }

    // Rows: x via wave-uniform (scalar) 16-B loads; no LDS staging, no barrier.
    const float* xrow = x + brow0 * IN_SIZE + i0;
    #pragma unroll
    for (int r = 0; r < BT; ++r) {
        const float4 xa = *reinterpret_cast<const float4*>(xrow + r * IN_SIZE);
        float s = bacc;
        conn(xa.x, W1[0], B1[0], W2[0], B2[0], W3[0], s);
        conn(xa.y, W1[1], B1[1], W2[1], B2[1], W3[1], s);
        conn(xa.z, W1[2], B1[2], W2[2], B2[2], W3[2], s);
        conn(xa.w, W1[3], B1[3], W2[3], B2[3], W3[3], s);
        ps[wv][r][o] = s;   // lanes stride-1 -> 2 lanes/bank = free
    }

    __syncthreads();   // the kernel's only barrier

    // Reduce 16 wave-partials per (r,o): 1024 outputs, 1024 threads -> 1 each.
    // ps[w][r][oo]: w-stride = 4 KiB -> bank = oo%32 for all 16 reads,
    // lanes spread across banks, 2 lanes/bank = conflict-free.
    {
        const int r = tid >> 6, oo = tid & 63;
        float v = 0.f;
        #pragma unroll
        for (int w = 0; w < WAVES; ++w) v += ps[w][r][oo];
        out[brow0 * OUT_SIZE + tid] = v;
    }
}

extern "C" void kernel_launch(void* const* d_in, const int* in_sizes, int n_in,
                              void* d_out, int out_size, void* d_ws, size_t ws_size,
                              hipStream_t stream) {
    const float* x  = (const float*)d_in[0];
    const float* w1 = (const float*)d_in[1];
    const float* b1 = (const float*)d_in[2];
    const float* w2 = (const float*)d_in[3];
    const float* b2 = (const float*)d_in[4];
    const float* w3 = (const float*)d_in[5];
    const float* b3 = (const float*)d_in[6];
    float* out = (float*)d_out;

    const int grid = BATCH / BT;   // 512 blocks x 1024 threads = 2 blocks/CU
    kan_kernel<<<grid, 1024, 0, stream>>>(x, w1, b1, w2, b2, w3, b3, out);
}